// Round 4
// baseline (399.850 us; speedup 1.0000x reference)
//
#include <hip/hip_runtime.h>

// Problem constants
constexpr int Bc  = 4;
constexpr int Sc  = 384;
constexpr int Dc  = 300;
constexpr int Ec  = 50;
constexpr int HDc = 150;          // D / L
constexpr int WHC = 2*HDc + Ec;   // 350, Wh row length

// ---------------------------------------------------------------------------
// prep_all: one launch does
//   (a) WT[300][600]  = [W0 | W1a | Wout]^T   (cols: 0..149 W0, 150..299 W1a,
//                                              300..599 Wout)
//   (b) W1bT[150][150] = W1[:, 300:450]^T
//   (c) sm column sums: [0..49] we, [64..213] w1, [224..373] w2, [384] sum(bh)
// ---------------------------------------------------------------------------
__global__ __launch_bounds__(256)
void prep_all(const float* __restrict__ W0, const float* __restrict__ W1,
              const float* __restrict__ Wout, const float* __restrict__ Wh,
              const float* __restrict__ bh,
              float* __restrict__ WT, float* __restrict__ W1bT,
              float* __restrict__ sm) {
    int idx = blockIdx.x * 256 + threadIdx.x;
    if (idx < 180000) {                       // WT
        int k = idx / 600, j = idx % 600;
        float v;
        if (j < 150)      v = W0[j * Dc + k];
        else if (j < 300) v = W1[(j - 150) * (Dc + HDc) + k];
        else              v = Wout[(j - 300) * Dc + k];
        WT[idx] = v;
        return;
    }
    idx -= 180000;
    if (idx < 22500) {                        // W1bT
        int k = idx / 150, j = idx % 150;
        W1bT[idx] = W1[j * (Dc + HDc) + Dc + k];
        return;
    }
    idx -= 22500;
    if (idx < 50) {                           // we colsum
        float s = 0.f;
        for (int e = 0; e < Ec; ++e) s += Wh[e * WHC + idx];
        sm[idx] = s;
    } else if (idx < 200) {                   // w1 colsum
        int h = idx - 50;
        float s = 0.f;
        for (int e = 0; e < Ec; ++e) s += Wh[e * WHC + Ec + h];
        sm[64 + h] = s;
    } else if (idx < 350) {                   // w2 colsum
        int h = idx - 200;
        float s = 0.f;
        for (int e = 0; e < Ec; ++e) s += Wh[e * WHC + Ec + HDc + h];
        sm[224 + h] = s;
    } else if (idx == 350) {                  // sum(bh)
        float s = 0.f;
        for (int e = 0; e < Ec; ++e) s += bh[e];
        sm[384] = s;
    }
}

// ---------------------------------------------------------------------------
// reduce_adj2: one coalesced pass over adj (B,S,S,E) via LDS staging.
//   A0[row] = (sum_e adj)/E ; wadj[row] = sum_e adj*we_colsum[e]
// ---------------------------------------------------------------------------
__global__ __launch_bounds__(256)
void reduce_adj2(const float* __restrict__ adj, const float* __restrict__ sm,
                 float* __restrict__ A0, float* __restrict__ wadj) {
    __shared__ float wec[64];
    __shared__ float tile[256 * 51];
    int t = threadIdx.x;
    if (t < Ec) wec[t] = sm[t];
    long base = (long)blockIdx.x * (256 * 50);
    const float4* p4 = (const float4*)(adj + base);
    for (int i = t; i < 3200; i += 256) {
        float4 v = p4[i];
        int e = 4 * i;
        const float* vp = (const float*)&v;
        #pragma unroll
        for (int j = 0; j < 4; ++j) {
            int ee = e + j;
            tile[(ee / 50) * 51 + (ee % 50)] = vp[j];
        }
    }
    __syncthreads();
    const float* row = tile + t * 51;
    float s = 0.f, w = 0.f;
    #pragma unroll
    for (int i = 0; i < 50; ++i) { float v = row[i]; s += v; w += v * wec[i]; }
    int r = blockIdx.x * 256 + t;
    A0[r]   = s * (1.0f / Ec);
    wadj[r] = w;
}

// ---------------------------------------------------------------------------
// rowgemm: block = 4 output rows, lane = output column(s). No LDS in K-loop,
// no barriers; latency hidden by TLP (384 blocks everywhere).
//   C[g, n] = sum_k A[g, k] * Bt[k, n]  [+ Dm[g,n]] [+ bscale*bias[n]] [relu]
// A1M:   A element = (wadj + s1[k] + s2[g] + sum_bh)/E, s12 from ws
// S12OUT: also emit s1/s2 row reductions of the (post-relu) output
// ---------------------------------------------------------------------------
template<int THREADS, int CITER, int A1M, int S12OUT, int HASD, int HASB, int RELU>
__global__ __launch_bounds__(THREADS)
void rowgemm(const float* __restrict__ A, const float* __restrict__ Bt,
             const float* __restrict__ Dm, const float* __restrict__ bias,
             float bscale, const float* __restrict__ s12,
             const float* __restrict__ sm, float* __restrict__ s12out,
             float* __restrict__ C,
             int N, int K, int lda, int ldb, int ldd, int ldc,
             int batchS, long sA, long sB) {
    int t = threadIdx.x;
    int g0 = blockIdx.x * 4;                 // 4 consecutive global rows
    int b = g0 / batchS;                     // flat kernels pass batchS=1536 -> 0
    const float* Ar0 = A + (long)b * sA + (long)(g0 - b * batchS) * lda;
    const float* Bb  = Bt + (long)b * sB;

    float tr[4];
    const float* s1p = nullptr;
    if constexpr (A1M) {
        s1p = s12 + (long)(2 * Sc) * b;
        float sbh = sm[384];
        #pragma unroll
        for (int r = 0; r < 4; ++r) tr[r] = s12[2 * (g0 + r) + 1] + sbh;
    }

    float acc[4][CITER];
    #pragma unroll
    for (int r = 0; r < 4; ++r)
        #pragma unroll
        for (int c = 0; c < CITER; ++c) acc[r][c] = 0.f;

    #pragma unroll 4
    for (int k = 0; k < K; ++k) {
        float bv[CITER];
        #pragma unroll
        for (int c = 0; c < CITER; ++c) {
            int nc = t + c * THREADS;
            bv[c] = (nc < N) ? Bb[(long)k * ldb + nc] : 0.f;
        }
        float s1k = 0.f;
        if constexpr (A1M) s1k = s1p[2 * k];
        #pragma unroll
        for (int r = 0; r < 4; ++r) {
            float a = Ar0[(long)r * lda + k];
            if constexpr (A1M) a = (a + s1k + tr[r]) * (1.0f / Ec);
            #pragma unroll
            for (int c = 0; c < CITER; ++c) acc[r][c] += a * bv[c];
        }
    }

    float p1[4], p2[4];
    if constexpr (S12OUT) {
        #pragma unroll
        for (int r = 0; r < 4; ++r) { p1[r] = 0.f; p2[r] = 0.f; }
    }

    #pragma unroll
    for (int r = 0; r < 4; ++r) {
        long g = g0 + r;
        #pragma unroll
        for (int c = 0; c < CITER; ++c) {
            int nc = t + c * THREADS;
            if (nc < N) {
                float v = acc[r][c];
                if constexpr (HASD) v += Dm[g * ldd + nc];
                if constexpr (HASB) v += bscale * bias[nc];
                if constexpr (RELU) v = fmaxf(v, 0.f);
                if constexpr (S12OUT) {
                    p1[r] += v * sm[64 + nc];
                    p2[r] += v * sm[224 + nc];
                }
                C[g * ldc + nc] = v;
            }
        }
    }

    if constexpr (S12OUT) {
        __shared__ float red[8][THREADS];
        #pragma unroll
        for (int r = 0; r < 4; ++r) {
            red[2 * r][t]     = p1[r];
            red[2 * r + 1][t] = p2[r];
        }
        __syncthreads();
        if (t < 8) {
            float s = 0.f;
            for (int i = 0; i < THREADS; ++i) s += red[t][i];
            s12out[2 * (g0 + (t >> 1)) + (t & 1)] = s;
        }
    }
}

extern "C" void kernel_launch(void* const* d_in, const int* in_sizes, int n_in,
                              void* d_out, int out_size, void* d_ws, size_t ws_size,
                              hipStream_t stream) {
    const float* adj  = (const float*)d_in[0];
    const float* X    = (const float*)d_in[1];
    const float* W0   = (const float*)d_in[2];
    const float* b0   = (const float*)d_in[3];
    const float* W1   = (const float*)d_in[4];
    const float* b1   = (const float*)d_in[5];
    const float* Wh   = (const float*)d_in[6];
    const float* bh   = (const float*)d_in[7];
    const float* Wout = (const float*)d_in[8];
    const float* bout = (const float*)d_in[9];
    float* out = (float*)d_out;

    // workspace layout (floats)
    float* ws   = (float*)d_ws;
    float* sm   = ws;                          // 512
    float* A0   = sm + 512;                    // 4*384*384
    float* wadj = A0 + Bc * Sc * Sc;           // 4*384*384
    float* R    = wadj + Bc * Sc * Sc;         // 1536 x 600: [P0 | Q1->P1 | X@Wout^T]
    float* Gbuf = R + (long)Bc * Sc * 600;     // 1536 x 300: [G0 | G1]
    float* s12  = Gbuf + (long)Bc * Sc * Dc;   // 1536 x 2 interleaved
    float* WT   = s12 + Bc * Sc * 2;           // 300 x 600
    float* W1bT = WT + 300 * 600;              // 150 x 150

    const int nrows = Bc * Sc * Sc;            // 589824 = 2304*256
    const int MT = Bc * Sc;                    // 1536 total rows
    const long MS = (long)Sc * Sc;             // adj batch stride
    const long RS = (long)Sc * 600;            // R batch stride (rows of one batch)

    // 1) transposed weights + column sums (one launch)
    prep_all<<<793, 256, 0, stream>>>(W0, W1, Wout, Wh, bh, WT, W1bT, sm);

    // 2) one HBM pass over adj: A0 (scaled) + weighted edge reduction
    reduce_adj2<<<nrows / 256, 256, 0, stream>>>(adj, sm, A0, wadj);

    // 3) R = X @ [W0|W1a|Wout]^T  (flat M=1536, N=600, K=300)
    rowgemm<256,3,0,0,0,0,0><<<MT / 4, 256, 0, stream>>>(
        X, WT, nullptr, nullptr, 0.f, nullptr, nullptr, nullptr, R,
        600, Dc, Dc, 600, 0, 600, MT, 0, 0);

    // 4) G0 = relu(A0 @ P0 + P0 + 2*b0), fused s1/s2 emission
    rowgemm<192,1,0,1,1,1,1><<<MT / 4, 192, 0, stream>>>(
        A0, R, R, b0, 2.0f, nullptr, sm, s12, Gbuf,
        HDc, Sc, Sc, 600, 600, Dc, Sc, MS, RS);

    // 5) P1 = Q1 + G0 @ W1b^T  (in-place into R[:,150:300]; flat, K=150)
    rowgemm<192,1,0,0,1,0,0><<<MT / 4, 192, 0, stream>>>(
        Gbuf, W1bT, R + HDc, nullptr, 0.f, nullptr, nullptr, nullptr, R + HDc,
        HDc, HDc, Dc, HDc, 600, 600, MT, 0, 0);

    // 6) G1 = relu(A1 @ P1 + P1 + 2*b1), A1 built on the fly from wadj+s12
    rowgemm<192,1,1,0,1,1,1><<<MT / 4, 192, 0, stream>>>(
        wadj, R + HDc, R + HDc, b1, 2.0f, s12, sm, nullptr, Gbuf + HDc,
        HDc, Sc, Sc, 600, 600, Dc, Sc, MS, RS);

    // 7) out = [G0|G1] @ Wout^T + X@Wout^T + bout  (flat, N=300, K=300)
    rowgemm<256,2,0,0,1,1,0><<<MT / 4, 256, 0, stream>>>(
        Gbuf, WT + 300, R + 300, bout, 1.0f, nullptr, nullptr, nullptr, out,
        Dc, Dc, Dc, 600, 600, Dc, MT, 0, 0);
}

// Round 5
// 345.118 us; speedup vs baseline: 1.1586x; 1.1586x over previous
//
#include <hip/hip_runtime.h>

// Problem constants
constexpr int Bc  = 4;
constexpr int Sc  = 384;
constexpr int Dc  = 300;
constexpr int Ec  = 50;
constexpr int HDc = 150;          // D / L
constexpr int WHC = 2*HDc + Ec;   // 350, Wh row length

// ---------------------------------------------------------------------------
// prep_all: (a) WT[300][600] = [W0 | W1a | Wout]^T   (k-major, ld 600)
//           (b) W1bT[150][150] = W1[:,300:450]^T     (k-major, ld 150)
//           (c) zero s12 (3072 floats)
//           (d) sm column sums: [0..49] we, [64..213] w1, [224..373] w2,
//               [384] sum(bh)
// ---------------------------------------------------------------------------
__global__ __launch_bounds__(256)
void prep_all(const float* __restrict__ W0, const float* __restrict__ W1,
              const float* __restrict__ Wout, const float* __restrict__ Wh,
              const float* __restrict__ bh,
              float* __restrict__ WT, float* __restrict__ W1bT,
              float* __restrict__ s12, float* __restrict__ sm) {
    int idx = blockIdx.x * 256 + threadIdx.x;
    if (idx < 180000) {                       // WT[k*600 + j]
        int k = idx / 600, j = idx % 600;
        float v;
        if (j < 150)      v = W0[j * Dc + k];
        else if (j < 300) v = W1[(j - 150) * (Dc + HDc) + k];
        else              v = Wout[(j - 300) * Dc + k];
        WT[idx] = v;
        return;
    }
    idx -= 180000;
    if (idx < 22500) {                        // W1bT[k*150 + j]
        int k = idx / 150, j = idx % 150;
        W1bT[idx] = W1[j * (Dc + HDc) + Dc + k];
        return;
    }
    idx -= 22500;
    if (idx < 3072) { s12[idx] = 0.f; return; }
    idx -= 3072;
    if (idx < 50) {                           // we colsum
        float s = 0.f;
        for (int e = 0; e < Ec; ++e) s += Wh[e * WHC + idx];
        sm[idx] = s;
    } else if (idx < 200) {                   // w1 colsum
        int h = idx - 50;
        float s = 0.f;
        for (int e = 0; e < Ec; ++e) s += Wh[e * WHC + Ec + h];
        sm[64 + h] = s;
    } else if (idx < 350) {                   // w2 colsum
        int h = idx - 200;
        float s = 0.f;
        for (int e = 0; e < Ec; ++e) s += Wh[e * WHC + Ec + HDc + h];
        sm[224 + h] = s;
    } else if (idx == 350) {                  // sum(bh)
        float s = 0.f;
        for (int e = 0; e < Ec; ++e) s += bh[e];
        sm[384] = s;
    }
}

// ---------------------------------------------------------------------------
// gemm_body: split-K row-wave GEMM. Block = 256 thr = 4 waves.
// Block tile = 4 rows x 64 cols; wave w accumulates over K-chunk w (K/4).
// A-row loads are wave-uniform (-> scalar loads, SMEM pipe); B loads are
// lane-coalesced (VMEM); FMAs on VALU. No LDS in the K-loop. Partials
// reduced 4->1 through `red` (1024 floats), then epilogue.
//   C[g,c] = sum_k A[g,k]*Bt[k,c] [+D] [+bscale*bias] [relu]
// A1M: A element = (wadj + s1[k] + s2[g] + sbh)/E  (s12 interleaved per row)
// S12OUT: emit s1/s2 row-reductions of output via wave-reduce + atomicAdd
// ---------------------------------------------------------------------------
template<int A1M, int HASD, int HASB, int RELU, int S12OUT>
__device__ __forceinline__ void gemm_body(
    float* red, int ct, int rt,
    const float* __restrict__ A, const float* __restrict__ Bt,
    const float* __restrict__ Dm, const float* __restrict__ bias, float bscale,
    const float* __restrict__ s12, const float* __restrict__ sm,
    float* __restrict__ s12out, float* __restrict__ C,
    int N, int K, int lda, int ldb, int ldd, int ldc,
    int rowsPerBatch, long sA, long sB)
{
    int tid  = threadIdx.x;
    int wave = tid >> 6, lane = tid & 63;
    int g0 = rt * 4;                       // global row base
    int b  = g0 / rowsPerBatch;
    int r0 = g0 - b * rowsPerBatch;        // local row base
    int c  = ct * 64 + lane;
    const float* Ab = A + (long)b * sA + (long)r0 * lda;
    const float* Bb = Bt + (long)b * sB;
    bool cok = (c < N);
    const float invE = 1.0f / Ec;

    float tr[4];
    const float* s1base = nullptr;
    if constexpr (A1M) {
        float sbh = sm[384];
        s1base = s12 + 2L * b * rowsPerBatch;    // s1(k) = s1base[2k]
        #pragma unroll
        for (int r = 0; r < 4; ++r) tr[r] = s12[2 * (g0 + r) + 1] + sbh;
    }

    int kb = (wave * K) >> 2, ke = ((wave + 1) * K) >> 2;
    float acc[4] = {0.f, 0.f, 0.f, 0.f};

    int k = kb;
    for (; k + 4 <= ke; k += 4) {
        float bv[4];
        #pragma unroll
        for (int j = 0; j < 4; ++j)
            bv[j] = cok ? Bb[(long)(k + j) * ldb + c] : 0.f;
        #pragma unroll
        for (int j = 0; j < 4; ++j) {
            float bvj = bv[j];
            float s1k = 0.f;
            if constexpr (A1M) { s1k = s1base[2 * (k + j)]; bvj *= invE; }
            #pragma unroll
            for (int r = 0; r < 4; ++r) {
                float a = Ab[(long)r * lda + k + j];
                if constexpr (A1M) a = a + s1k + tr[r];
                acc[r] = fmaf(a, bvj, acc[r]);
            }
        }
    }
    for (; k < ke; ++k) {
        float bvj = cok ? Bb[(long)k * ldb + c] : 0.f;
        float s1k = 0.f;
        if constexpr (A1M) { s1k = s1base[2 * k]; bvj *= invE; }
        #pragma unroll
        for (int r = 0; r < 4; ++r) {
            float a = Ab[(long)r * lda + k];
            if constexpr (A1M) a = a + s1k + tr[r];
            acc[r] = fmaf(a, bvj, acc[r]);
        }
    }

    // stash per-wave partials: red[wave][row][lane]
    #pragma unroll
    for (int r = 0; r < 4; ++r) red[wave * 256 + r * 64 + lane] = acc[r];
    __syncthreads();

    // final: thread tid -> row (tid>>6), col lane; stride-256 reads are
    // conflict-free per instruction (consecutive addresses across lanes)
    int g = g0 + (tid >> 6);
    float v = red[tid] + red[256 + tid] + red[512 + tid] + red[768 + tid];
    float p1 = 0.f, p2 = 0.f;
    if (cok) {
        if constexpr (HASD) v += Dm[(long)g * ldd + c];
        if constexpr (HASB) v += bscale * bias[c];
        if constexpr (RELU) v = fmaxf(v, 0.f);
        C[(long)g * ldc + c] = v;
        if constexpr (S12OUT) { p1 = v * sm[64 + c]; p2 = v * sm[224 + c]; }
    }
    if constexpr (S12OUT) {
        #pragma unroll
        for (int off = 32; off; off >>= 1) {
            p1 += __shfl_down(p1, off);
            p2 += __shfl_down(p2, off);
        }
        if (lane == 0) {
            atomicAdd(&s12out[2 * g],     p1);
            atomicAdd(&s12out[2 * g + 1], p2);
        }
    }
}

template<int A1M, int HASD, int HASB, int RELU, int S12OUT>
__global__ __launch_bounds__(256)
void sgemm(const float* __restrict__ A, const float* __restrict__ Bt,
           const float* __restrict__ Dm, const float* __restrict__ bias,
           float bscale, const float* __restrict__ s12,
           const float* __restrict__ sm, float* __restrict__ s12out,
           float* __restrict__ C,
           int N, int K, int lda, int ldb, int ldd, int ldc,
           int rowsPerBatch, long sA, long sB) {
    __shared__ float red[1024];
    gemm_body<A1M, HASD, HASB, RELU, S12OUT>(
        red, blockIdx.x, blockIdx.y, A, Bt, Dm, bias, bscale, s12, sm, s12out,
        C, N, K, lda, ldb, ldd, ldc, rowsPerBatch, sA, sB);
}

// ---------------------------------------------------------------------------
// front: blocks [0,2304) = adj reduction (HBM-bound, LDS-staged coalesced);
//        blocks [2304,6144) = R = X @ [W0|W1a|Wout]^T (VALU-bound, hides
//        under the adj HBM stream).
// ---------------------------------------------------------------------------
__global__ __launch_bounds__(256)
void front(const float* __restrict__ adj, const float* __restrict__ sm,
           float* __restrict__ A0, float* __restrict__ wadj,
           const float* __restrict__ X, const float* __restrict__ WT,
           float* __restrict__ R) {
    __shared__ float lds[256 * 51 + 64];
    if (blockIdx.x < 2304) {
        float* tile = lds;
        float* wec  = lds + 256 * 51;
        int t = threadIdx.x;
        if (t < Ec) wec[t] = sm[t];
        long base = (long)blockIdx.x * (256 * 50);
        const float4* p4 = (const float4*)(adj + base);
        for (int i = t; i < 3200; i += 256) {
            float4 v = p4[i];
            int e = 4 * i;
            const float* vp = (const float*)&v;
            #pragma unroll
            for (int j = 0; j < 4; ++j) {
                int ee = e + j;
                tile[(ee / 50) * 51 + (ee % 50)] = vp[j];
            }
        }
        __syncthreads();
        const float* row = tile + t * 51;
        float s = 0.f, w = 0.f;
        #pragma unroll
        for (int i = 0; i < 50; ++i) { float v = row[i]; s += v; w += v * wec[i]; }
        int r = blockIdx.x * 256 + t;
        A0[r]   = s * (1.0f / Ec);
        wadj[r] = w;
    } else {
        int lin = blockIdx.x - 2304;          // 3840 blocks: 10 coltiles x 384
        gemm_body<0,0,0,0,0>(lds, lin % 10, lin / 10,
                             X, WT, nullptr, nullptr, 0.f, nullptr, nullptr,
                             nullptr, R,
                             600, Dc, Dc, 600, 0, 600, Bc * Sc, 0, 0);
    }
}

extern "C" void kernel_launch(void* const* d_in, const int* in_sizes, int n_in,
                              void* d_out, int out_size, void* d_ws, size_t ws_size,
                              hipStream_t stream) {
    const float* adj  = (const float*)d_in[0];
    const float* X    = (const float*)d_in[1];
    const float* W0   = (const float*)d_in[2];
    const float* b0   = (const float*)d_in[3];
    const float* W1   = (const float*)d_in[4];
    const float* b1   = (const float*)d_in[5];
    const float* Wh   = (const float*)d_in[6];
    const float* bh   = (const float*)d_in[7];
    const float* Wout = (const float*)d_in[8];
    const float* bout = (const float*)d_in[9];
    float* out = (float*)d_out;

    // workspace layout (floats)
    float* ws   = (float*)d_ws;
    float* sm   = ws;                          // 512
    float* A0   = sm + 512;                    // 4*384*384
    float* wadj = A0 + Bc * Sc * Sc;           // 4*384*384
    float* R    = wadj + Bc * Sc * Sc;         // 1536 x 600: [P0 | Q1->P1 | X@Wout^T]
    float* Gbuf = R + (long)Bc * Sc * 600;     // 1536 x 300: [G0 | G1]
    float* s12  = Gbuf + (long)Bc * Sc * Dc;   // 1536 x 2 interleaved (s1,s2)
    float* WT   = s12 + Bc * Sc * 2;           // 300 x 600
    float* W1bT = WT + 300 * 600;              // 150 x 150

    const int MT = Bc * Sc;                    // 1536 global rows
    const long AS = (long)Sc * Sc;             // adj batch stride
    const long RS = (long)Sc * 600;            // R batch stride

    // 1) transposed weights + column sums + zero s12
    prep_all<<<806, 256, 0, stream>>>(W0, W1, Wout, Wh, bh, WT, W1bT, s12, sm);

    // 2) adj reduction (2304 blocks) || R = X @ [W0|W1a|Wout]^T (3840 blocks)
    front<<<6144, 256, 0, stream>>>(adj, sm, A0, wadj, X, WT, R);

    // 3) G0 = relu(A0 @ P0 + P0 + 2*b0); fused s1/s2 atomically into s12
    sgemm<0,1,1,1,1><<<dim3(3, 384), 256, 0, stream>>>(
        A0, R, R, b0, 2.0f, nullptr, sm, s12, Gbuf,
        HDc, Sc, Sc, 600, 600, Dc, Sc, AS, RS);

    // 4) P1 = Q1 + G0 @ W1b^T   (in-place into R[:,150:300], K=150)
    sgemm<0,1,0,0,0><<<dim3(3, 384), 256, 0, stream>>>(
        Gbuf, W1bT, R + HDc, nullptr, 0.f, nullptr, nullptr, nullptr, R + HDc,
        HDc, HDc, Dc, HDc, 600, 600, MT, 0, 0);

    // 5) G1 = relu(A1 @ P1 + P1 + 2*b1); A1 from wadj+s12 on the fly
    sgemm<1,1,1,1,0><<<dim3(3, 384), 256, 0, stream>>>(
        wadj, R + HDc, R + HDc, b1, 2.0f, s12, sm, nullptr, Gbuf + HDc,
        HDc, Sc, Sc, 600, 600, Dc, Sc, AS, RS);

    // 6) out = [G0|G1] @ Wout^T + X@Wout^T + bout
    sgemm<0,1,1,0,0><<<dim3(5, 384), 256, 0, stream>>>(
        Gbuf, WT + 300, R + 300, bout, 1.0f, nullptr, nullptr, nullptr, out,
        Dc, Dc, Dc, 600, 600, Dc, MT, 0, 0);
}